// Round 11
// baseline (99.369 us; speedup 1.0000x reference)
//
#include <hip/hip_runtime.h>
#include <math.h>

#define NUM_T   1000
#define NUM_R   8
#define NBINS   200
#define FPB     2                       // frames per block -> grid 8*500=4000
#define TTSZ    224                     // padded threshold table (inf tail)
#define TYSTR   217                     // u32 rows per type: 200 bins + 17 dump
#define NCOL    4                       // histogram columns (tid&3)
#define HWORDS  (3*TYSTR*NCOL)          // 2604 u32 words

__device__ __forceinline__ float approx_sqrt(float x) {
    float r; asm("v_sqrt_f32 %0, %1" : "=v"(r) : "v"(x)); return r;
}
__device__ __forceinline__ float fract_(float x) {
#if __has_builtin(__builtin_amdgcn_fractf)
    return __builtin_amdgcn_fractf(x);
#else
    return x - floorf(x);
#endif
}

// ---------------------------------------------------------------------------
// Bit-exact binning on squared distances (validated R1-R9, absmax 3.906e-3):
//   TT[k] = min{s : sqrtf(s) >= bins[k]}; TT[200] = Tp (d<=10 edge).
//   Fast path k=(int)z, z=v_sqrt(400s), exact unless frac(z) within +-2e-4
//   of an integer (boundary-image analysis R3). Ambiguous -> whole-wave-vote
//   slow path: k += (s>=TT[k+1]) - (s<TT[k]) (no-op for exact lanes);
//   k<0 (s<TT[0], incl. d==0) -> k=216. No explicit range test: d>10 lands
//   in PER-TYPE dump rows k=200..216 (TYSTR=217), never flushed.
// Histogram: u32, 4 columns. word = (type*217 + k)*4 + (tid&3). (R8 layout;
//   R6 proved conflict count is not the binding term, so no more copies.)
// R10: DS-read demand + overlap.
//   (a) Rotation read-pairing: thread holds pi_a=pos[l], pi_b=pos[l+1]; one
//       read pj=pos[l+k] feeds sep-k body (pi_a,pj) and sep-(k-1) body
//       (pi_b,pj). Wave q reads k=8it+2q+2 (it=0..3): even seps 2..32 as _a,
//       odd seps 1..31 as _b. Exact coverage: (l+1, l+k) over l = all 64
//       sep-(k-1) pairs (wrap: pos[64]==pos[0] in dup'd arrays). Sep-32
//       keeps the l<32 half-coverage guard; sep-31 from the same read full.
//       Rotation j-reads 24 -> 12 per thread-frame.
//   (b) Wave stagger: wave q runs the 5 sections starting at (q mod 5)
//       (uniform switch) so post-barrier load bursts and atomic bursts of
//       different waves interleave on the DS pipe instead of colliding.
// Pair enumeration (symmetric types once, weight 2) otherwise as R4-R9.
// ---------------------------------------------------------------------------
__global__ __launch_bounds__(256, 8) void rdf_hist_kernel(
    const float* __restrict__ radii,      // [T][R][192][3]
    const float* __restrict__ lat,        // [3]
    unsigned int* __restrict__ gh)        // [R][3][200]
{
    #pragma clang fp contract(off)
    __shared__ float4 posOx[96], posH0[96], posH1[96];
    __shared__ float TT[TTSZ];
    __shared__ __align__(16) unsigned int hist[HWORDS];

    const int tid = threadIdx.x;

    if (tid < TTSZ) {
        float v;
        if (tid <= 200) {
            float b;
            if (tid < NBINS) {
                const double step = (10.0 - 1e-6) / 200.0;
                b = (float)(1e-6 + (double)tid * step);
            } else {
                b = __uint_as_float(__float_as_uint(10.0f) + 1u); // nextafter(10,inf)
            }
            unsigned lo = 0u, hi = 0x7F800000u;
            while (lo < hi) {
                unsigned mid = (lo + hi) >> 1;
                if (sqrtf(__uint_as_float(mid)) >= b) hi = mid; else lo = mid + 1;
            }
            v = __uint_as_float(lo);
        } else {
            v = __uint_as_float(0x7F800000u);   // +inf padding
        }
        TT[tid] = v;
    }
    for (int i = tid; i < HWORDS; i += 256) hist[i] = 0u;

    const float Lx = lat[0], Ly = lat[1], Lz = lat[2];
    __syncthreads();

    const int col = tid & (NCOL - 1);

#define PAIRV(PI, PJ, TB, W)                                                 \
    {                                                                        \
        float tx = (PI).x - (PJ).x;                                          \
        float ty = (PI).y - (PJ).y;                                          \
        float tz = (PI).z - (PJ).z;                                          \
        float ax = fminf(fabsf(tx), Lx - fabsf(tx));                         \
        float ay = fminf(fabsf(ty), Ly - fabsf(ty));                         \
        float az = fminf(fabsf(tz), Lz - fabsf(tz));                         \
        float s  = (ax*ax + ay*ay) + az*az;                                  \
        float z  = approx_sqrt(s * 400.0f);                                  \
        int   k  = (int)z;                                                   \
        float m  = fract_(z);                                                \
        bool amb = fabsf(m - 0.5f) > 0.49980f;                               \
        if (__builtin_expect(__any(amb), 0)) {                               \
            float tlo = TT[k], thi = TT[k + 1];                              \
            k += ((s >= thi) ? 1 : 0) - ((s < tlo) ? 1 : 0);                 \
            if (k < 0) k = 216;                                              \
        }                                                                    \
        atomicAdd(&hist[(TB) + (k << 2)], (W));                              \
    }

// rotation section with read-pairing: 4 j-reads -> 8 bodies.
// jb2 = l + 2q + 2; read sep k = 8it+2q+2; _b body sep k-1.
#define ROTSEC(ARR, PIA, PIB, TB)                                            \
    {                                                                        \
        float4 pja[4];                                                       \
        _Pragma("unroll")                                                    \
        for (int it = 0; it < 4; ++it) pja[it] = ARR[jb2 + 8*it];            \
        _Pragma("unroll")                                                    \
        for (int it = 0; it < 4; ++it) {                                     \
            PAIRV(PIB, pja[it], TB, 2u)                                      \
            if (it < 3 || q < 3 || l < 32) PAIRV(PIA, pja[it], TB, 2u)       \
        }                                                                    \
    }

    const int rep   = blockIdx.x & (NUM_R - 1);
    const int chunk = blockIdx.x / NUM_R;
    const int l     = tid & 63;
    const int q     = tid >> 6;                    // wave id 0..3 (uniform)
    const int tbOO  = col;                         // type 0 rows
    const int tbHH  = col + (TYSTR << 2);          // type 1 rows
    const int tbHO  = col + (2 * TYSTR << 2);      // type 2 rows

    // prefetch frame 0 raw coords
    float rvx = 0.f, rvy = 0.f, rvz = 0.f;
    {
        const float* s0 = radii + ((size_t)(chunk * FPB) * NUM_R + rep) * (192 * 3);
        if (tid < 192) { rvx = s0[tid*3+0]; rvy = s0[tid*3+1]; rvz = s0[tid*3+2]; }
    }

    #pragma unroll 1
    for (int f = 0; f < FPB; ++f) {
        __syncthreads();
        if (tid < 192) {
            float ux = rvx / Lx; ux -= floorf(ux);
            float uy = rvy / Ly; uy -= floorf(uy);
            float uz = rvz / Lz; uz -= floorf(uz);
            float4 p = make_float4(ux*Lx, uy*Ly, uz*Lz, 0.0f);
            if (tid < 64)       { posOx[tid] = p;  if (tid < 32) posOx[tid+64] = p; }
            else if (tid < 128) { int h = tid-64;  posH0[h] = p; if (h < 32) posH0[h+64] = p; }
            else                { int h = tid-128; posH1[h] = p; if (h < 32) posH1[h+64] = p; }
        }
        __syncthreads();

        if (f + 1 < FPB && tid < 192) {   // prefetch next frame during compute
            const float* s1 = radii + ((size_t)(chunk * FPB + f + 1) * NUM_R + rep) * (192 * 3);
            rvx = s1[tid*3+0]; rvy = s1[tid*3+1]; rvz = s1[tid*3+2];
        }

        const float4 piO  = posOx[l];
        const float4 piOb = posOx[l + 1];
        const float4 pi0  = posH0[l];
        const float4 pi0b = posH0[l + 1];
        const float4 pi1  = posH1[l];
        const float4 pi1b = posH1[l + 1];
        const int jb2 = l + 2*q + 2;

        // ---- 5 sections, start offset staggered by wave id ----
        #pragma unroll
        for (int sid = 0; sid < 5; ++sid) {
            switch ((sid + q) % 5) {
            case 0:   // O-O diag rotation
                ROTSEC(posOx, piO, piOb, tbOO)
                break;
            case 1:   // H0 diag rotation
                ROTSEC(posH0, pi0, pi0b, tbHH)
                break;
            case 2:   // H1 diag rotation
                ROTSEC(posH1, pi1, pi1b, tbHH)
                break;
            case 3:   // HH cross (H0 x H1), weight 2, batched uniform reads
                #pragma unroll 1
                for (int b2 = 0; b2 < 2; ++b2) {
                    float4 pjc[8];
                    #pragma unroll
                    for (int jj = 0; jj < 8; ++jj) pjc[jj] = posH1[q*16 + b2*8 + jj];
                    #pragma unroll
                    for (int jj = 0; jj < 8; ++jj) PAIRV(pi0, pjc[jj], tbHH, 2u)
                }
                break;
            default:  // H-O ordered, weight 1: each uniform O feeds both H rows
                #pragma unroll 1
                for (int b2 = 0; b2 < 2; ++b2) {
                    float4 pjc[8];
                    #pragma unroll
                    for (int jj = 0; jj < 8; ++jj) pjc[jj] = posOx[q*16 + b2*8 + jj];
                    #pragma unroll
                    for (int jj = 0; jj < 8; ++jj) {
                        PAIRV(pi0, pjc[jj], tbHO, 1u)
                        PAIRV(pi1, pjc[jj], tbHO, 1u)
                    }
                }
                break;
            }
        }
    }
#undef ROTSEC
#undef PAIRV

    __syncthreads();
    // flush logical rows (type p, bin b): one b128 read of the 4 columns.
    for (int idx = tid; idx < 3 * NBINS; idx += 256) {
        const int p = idx / 200;
        const int b = idx - p * 200;
        const uint4 v = *reinterpret_cast<const uint4*>(&hist[(p * TYSTR + b) << 2]);
        unsigned sum = (v.x + v.y) + (v.z + v.w);
        if (sum) atomicAdd(&gh[rep * 3 * NBINS + idx], sum);
    }
}

// ---------------------------------------------------------------------------
__global__ __launch_bounds__(256) void rdf_final_kernel(
    const unsigned int* __restrict__ gh,  // [R][3][200]
    const float* __restrict__ gt,         // [3][200]
    const float* __restrict__ lat,        // [3]
    float* __restrict__ out)              // [R][600] then [R] maxmae
{
    #pragma clang fp contract(off)
    const int rep = blockIdx.x;
    const int tid = threadIdx.x;
    __shared__ float bins[NBINS + 1];
    __shared__ float red[256];

    for (int i = tid; i <= NBINS; i += 256) {
        const double step = (10.0 - 1e-6) / 200.0;
        bins[i] = (i == NBINS) ? 10.0f : (float)(1e-6 + (double)i * step);
    }
    __syncthreads();

    const float vol = (lat[0] * lat[1]) * lat[2];
    const float C   = 4.18879020478639053f;   // float(4/3*pi)
    const int npairs[3] = { NUM_T*64*64, NUM_T*128*128, NUM_T*128*64 };

    float maxmae = -3.0e38f;
    for (int p = 0; p < 3; ++p) {
        float diff = 0.0f;
        if (tid < NBINS) {
            float b0 = bins[tid], b1 = bins[tid + 1];
            float shell = C * (b1*b1*b1 - b0*b0*b0);
            float rho = (float)npairs[p] / vol;
            float g = (float)gh[(rep*3 + p)*NBINS + tid] / (rho * shell);
            out[rep*3*NBINS + p*NBINS + tid] = g;
            diff = fabsf(g - gt[p*NBINS + tid]);
        }
        red[tid] = diff;
        __syncthreads();
        for (int s = 128; s > 0; s >>= 1) {
            if (tid < s) red[tid] += red[tid + s];
            __syncthreads();
        }
        if (tid == 0) {
            float mae = 10.0f * (red[0] / 200.0f);
            if (mae > maxmae) maxmae = mae;
        }
        __syncthreads();
    }
    if (tid == 0) out[NUM_R*3*NBINS + rep] = maxmae;
}

// ---------------------------------------------------------------------------
extern "C" void kernel_launch(void* const* d_in, const int* in_sizes, int n_in,
                              void* d_out, int out_size, void* d_ws, size_t ws_size,
                              hipStream_t stream) {
    const float* radii = (const float*)d_in[0];
    const float* lat   = (const float*)d_in[1];
    const float* gt    = (const float*)d_in[2];
    unsigned int* gh   = (unsigned int*)d_ws;

    hipMemsetAsync(gh, 0, NUM_R * 3 * NBINS * sizeof(unsigned int), stream);

    dim3 grid(NUM_R * (NUM_T / FPB));     // 8 * 500 = 4000 blocks
    hipLaunchKernelGGL(rdf_hist_kernel, grid, dim3(256), 0, stream,
                       radii, lat, gh);
    hipLaunchKernelGGL(rdf_final_kernel, dim3(NUM_R), dim3(256), 0, stream,
                       gh, gt, lat, (float*)d_out);
}

// Round 12
// 92.081 us; speedup vs baseline: 1.0792x; 1.0792x over previous
//
#include <hip/hip_runtime.h>
#include <math.h>

#define NUM_T   1000
#define NUM_R   8
#define NBINS   200
#define FPB     2                       // frames per block -> grid 8*500=4000
#define TTSZ    224                     // padded threshold table (inf tail)
#define TYSTR   217                     // u32 rows per type: 200 bins + 17 dump
#define NCOL    4                       // histogram columns (tid&3)
#define HWORDS  (3*TYSTR*NCOL)          // 2604 u32 words

__device__ __forceinline__ float approx_sqrt(float x) {
    float r; asm("v_sqrt_f32 %0, %1" : "=v"(r) : "v"(x)); return r;
}
__device__ __forceinline__ float fract_(float x) {
#if __has_builtin(__builtin_amdgcn_fractf)
    return __builtin_amdgcn_fractf(x);
#else
    return x - floorf(x);
#endif
}

// ---------------------------------------------------------------------------
// Bit-exact binning on squared distances (validated R1-R10, absmax 3.906e-3):
//   TT[k] = min{s : sqrtf(s) >= bins[k]}; TT[200] = Tp (d<=10 edge).
//   Fast path k=(int)z, z=v_sqrt(400s), exact unless frac(z) within +-2e-4
//   of an integer (boundary-image analysis R3). Ambiguous -> whole-wave-vote
//   slow path: k += (s>=TT[k+1]) - (s<TT[k]) (no-op for exact lanes);
//   k<0 (s<TT[0], incl. d==0) -> k=216. No explicit range test: d>10 lands
//   in PER-TYPE dump rows k=200..216 (TYSTR=217), never flushed.
// Histogram: u32, 4 columns. word = (type*217 + k)*4 + (tid&3).
// R11: read-pairing ONLY, straight-line (R10's switch-stagger caused scratch
//   spill: WRITE_SIZE 9.3->53.6 MB; confounded the pairing test).
//   Rotation sections: thread holds pi_a=pos[l], pi_b=pos[l+1]; one read
//   pj=pos[l+sep] feeds sep body (pi_a,pj) and sep-1 body (pi_b,pj).
//   Wave q reads sep = 8it+2q+2 (it=0..3): even seps 2..32 as _a, odd seps
//   1..31 as _b (coverage validated R10). Sep-32 keeps the l<32 guard.
//   Rotation j-reads 24 -> 12 per thread-frame (DS reads 56 -> 44).
// Pair enumeration (symmetric types once, weight 2) otherwise as R9.
// ---------------------------------------------------------------------------
__global__ __launch_bounds__(256, 8) void rdf_hist_kernel(
    const float* __restrict__ radii,      // [T][R][192][3]
    const float* __restrict__ lat,        // [3]
    unsigned int* __restrict__ gh)        // [R][3][200]
{
    #pragma clang fp contract(off)
    __shared__ float4 posOx[96], posH0[96], posH1[96];
    __shared__ float TT[TTSZ];
    __shared__ __align__(16) unsigned int hist[HWORDS];

    const int tid = threadIdx.x;

    if (tid < TTSZ) {
        float v;
        if (tid <= 200) {
            float b;
            if (tid < NBINS) {
                const double step = (10.0 - 1e-6) / 200.0;
                b = (float)(1e-6 + (double)tid * step);
            } else {
                b = __uint_as_float(__float_as_uint(10.0f) + 1u); // nextafter(10,inf)
            }
            unsigned lo = 0u, hi = 0x7F800000u;
            while (lo < hi) {
                unsigned mid = (lo + hi) >> 1;
                if (sqrtf(__uint_as_float(mid)) >= b) hi = mid; else lo = mid + 1;
            }
            v = __uint_as_float(lo);
        } else {
            v = __uint_as_float(0x7F800000u);   // +inf padding
        }
        TT[tid] = v;
    }
    for (int i = tid; i < HWORDS; i += 256) hist[i] = 0u;

    const float Lx = lat[0], Ly = lat[1], Lz = lat[2];
    __syncthreads();

    const int col = tid & (NCOL - 1);

#define PAIRV(PI, PJ, TB, W)                                                 \
    {                                                                        \
        float tx = (PI).x - (PJ).x;                                          \
        float ty = (PI).y - (PJ).y;                                          \
        float tz = (PI).z - (PJ).z;                                          \
        float ax = fminf(fabsf(tx), Lx - fabsf(tx));                         \
        float ay = fminf(fabsf(ty), Ly - fabsf(ty));                         \
        float az = fminf(fabsf(tz), Lz - fabsf(tz));                         \
        float s  = (ax*ax + ay*ay) + az*az;                                  \
        float z  = approx_sqrt(s * 400.0f);                                  \
        int   k  = (int)z;                                                   \
        float m  = fract_(z);                                                \
        bool amb = fabsf(m - 0.5f) > 0.49980f;                               \
        if (__builtin_expect(__any(amb), 0)) {                               \
            float tlo = TT[k], thi = TT[k + 1];                              \
            k += ((s >= thi) ? 1 : 0) - ((s < tlo) ? 1 : 0);                 \
            if (k < 0) k = 216;                                              \
        }                                                                    \
        atomicAdd(&hist[(TB) + (k << 2)], (W));                              \
    }

// rotation section with read-pairing: 4 batched j-reads -> 8 bodies.
// read sep = 8it+2q+2 (addr jb2+8it); _a body sep, _b body sep-1.
#define ROTSEC(ARR, PIA, PIB, TB)                                            \
    {                                                                        \
        float4 pja[4];                                                       \
        _Pragma("unroll")                                                    \
        for (int it = 0; it < 4; ++it) pja[it] = ARR[jb2 + 8*it];            \
        _Pragma("unroll")                                                    \
        for (int it = 0; it < 4; ++it) {                                     \
            PAIRV(PIB, pja[it], TB, 2u)                                      \
            if (it < 3 || q < 3 || l < 32) PAIRV(PIA, pja[it], TB, 2u)       \
        }                                                                    \
    }

    const int rep   = blockIdx.x & (NUM_R - 1);
    const int chunk = blockIdx.x / NUM_R;
    const int l     = tid & 63;
    const int q     = tid >> 6;                    // wave id 0..3 (uniform)
    const int tbOO  = col;                         // type 0 rows
    const int tbHH  = col + (TYSTR << 2);          // type 1 rows
    const int tbHO  = col + (2 * TYSTR << 2);      // type 2 rows

    // prefetch frame 0 raw coords
    float rvx = 0.f, rvy = 0.f, rvz = 0.f;
    {
        const float* s0 = radii + ((size_t)(chunk * FPB) * NUM_R + rep) * (192 * 3);
        if (tid < 192) { rvx = s0[tid*3+0]; rvy = s0[tid*3+1]; rvz = s0[tid*3+2]; }
    }

    #pragma unroll 1
    for (int f = 0; f < FPB; ++f) {
        __syncthreads();
        if (tid < 192) {
            float ux = rvx / Lx; ux -= floorf(ux);
            float uy = rvy / Ly; uy -= floorf(uy);
            float uz = rvz / Lz; uz -= floorf(uz);
            float4 p = make_float4(ux*Lx, uy*Ly, uz*Lz, 0.0f);
            if (tid < 64)       { posOx[tid] = p;  if (tid < 32) posOx[tid+64] = p; }
            else if (tid < 128) { int h = tid-64;  posH0[h] = p; if (h < 32) posH0[h+64] = p; }
            else                { int h = tid-128; posH1[h] = p; if (h < 32) posH1[h+64] = p; }
        }
        __syncthreads();

        if (f + 1 < FPB && tid < 192) {   // prefetch next frame during compute
            const float* s1 = radii + ((size_t)(chunk * FPB + f + 1) * NUM_R + rep) * (192 * 3);
            rvx = s1[tid*3+0]; rvy = s1[tid*3+1]; rvz = s1[tid*3+2];
        }

        const int jb2 = l + 2*q + 2;

        // ---- O-O diag rotation (paired) ----
        {
            const float4 piA = posOx[l], piB = posOx[l + 1];
            ROTSEC(posOx, piA, piB, tbOO)
        }
        // ---- H0 diag rotation (paired) ----
        {
            const float4 piA = posH0[l], piB = posH0[l + 1];
            ROTSEC(posH0, piA, piB, tbHH)
        }
        // ---- H1 diag rotation (paired) ----
        {
            const float4 piA = posH1[l], piB = posH1[l + 1];
            ROTSEC(posH1, piA, piB, tbHH)
        }

        const float4 pi0 = posH0[l];
        const float4 pi1 = posH1[l];

        // ---- HH cross (H0 x H1), weight 2: batched uniform reads ----
        #pragma unroll 1
        for (int b2 = 0; b2 < 2; ++b2) {
            float4 pjc[8];
            #pragma unroll
            for (int jj = 0; jj < 8; ++jj) pjc[jj] = posH1[q*16 + b2*8 + jj];
            #pragma unroll
            for (int jj = 0; jj < 8; ++jj) PAIRV(pi0, pjc[jj], tbHH, 2u)
        }
        // ---- H-O ordered, weight 1: each uniform O feeds both H rows ----
        #pragma unroll 1
        for (int b2 = 0; b2 < 2; ++b2) {
            float4 pjc[8];
            #pragma unroll
            for (int jj = 0; jj < 8; ++jj) pjc[jj] = posOx[q*16 + b2*8 + jj];
            #pragma unroll
            for (int jj = 0; jj < 8; ++jj) {
                PAIRV(pi0, pjc[jj], tbHO, 1u)
                PAIRV(pi1, pjc[jj], tbHO, 1u)
            }
        }
    }
#undef ROTSEC
#undef PAIRV

    __syncthreads();
    // flush logical rows (type p, bin b): one b128 read of the 4 columns.
    for (int idx = tid; idx < 3 * NBINS; idx += 256) {
        const int p = idx / 200;
        const int b = idx - p * 200;
        const uint4 v = *reinterpret_cast<const uint4*>(&hist[(p * TYSTR + b) << 2]);
        unsigned sum = (v.x + v.y) + (v.z + v.w);
        if (sum) atomicAdd(&gh[rep * 3 * NBINS + idx], sum);
    }
}

// ---------------------------------------------------------------------------
__global__ __launch_bounds__(256) void rdf_final_kernel(
    const unsigned int* __restrict__ gh,  // [R][3][200]
    const float* __restrict__ gt,         // [3][200]
    const float* __restrict__ lat,        // [3]
    float* __restrict__ out)              // [R][600] then [R] maxmae
{
    #pragma clang fp contract(off)
    const int rep = blockIdx.x;
    const int tid = threadIdx.x;
    __shared__ float bins[NBINS + 1];
    __shared__ float red[256];

    for (int i = tid; i <= NBINS; i += 256) {
        const double step = (10.0 - 1e-6) / 200.0;
        bins[i] = (i == NBINS) ? 10.0f : (float)(1e-6 + (double)i * step);
    }
    __syncthreads();

    const float vol = (lat[0] * lat[1]) * lat[2];
    const float C   = 4.18879020478639053f;   // float(4/3*pi)
    const int npairs[3] = { NUM_T*64*64, NUM_T*128*128, NUM_T*128*64 };

    float maxmae = -3.0e38f;
    for (int p = 0; p < 3; ++p) {
        float diff = 0.0f;
        if (tid < NBINS) {
            float b0 = bins[tid], b1 = bins[tid + 1];
            float shell = C * (b1*b1*b1 - b0*b0*b0);
            float rho = (float)npairs[p] / vol;
            float g = (float)gh[(rep*3 + p)*NBINS + tid] / (rho * shell);
            out[rep*3*NBINS + p*NBINS + tid] = g;
            diff = fabsf(g - gt[p*NBINS + tid]);
        }
        red[tid] = diff;
        __syncthreads();
        for (int s = 128; s > 0; s >>= 1) {
            if (tid < s) red[tid] += red[tid + s];
            __syncthreads();
        }
        if (tid == 0) {
            float mae = 10.0f * (red[0] / 200.0f);
            if (mae > maxmae) maxmae = mae;
        }
        __syncthreads();
    }
    if (tid == 0) out[NUM_R*3*NBINS + rep] = maxmae;
}

// ---------------------------------------------------------------------------
extern "C" void kernel_launch(void* const* d_in, const int* in_sizes, int n_in,
                              void* d_out, int out_size, void* d_ws, size_t ws_size,
                              hipStream_t stream) {
    const float* radii = (const float*)d_in[0];
    const float* lat   = (const float*)d_in[1];
    const float* gt    = (const float*)d_in[2];
    unsigned int* gh   = (unsigned int*)d_ws;

    hipMemsetAsync(gh, 0, NUM_R * 3 * NBINS * sizeof(unsigned int), stream);

    dim3 grid(NUM_R * (NUM_T / FPB));     // 8 * 500 = 4000 blocks
    hipLaunchKernelGGL(rdf_hist_kernel, grid, dim3(256), 0, stream,
                       radii, lat, gh);
    hipLaunchKernelGGL(rdf_final_kernel, dim3(NUM_R), dim3(256), 0, stream,
                       gh, gt, lat, (float*)d_out);
}